// Round 1
// baseline (1338.843 us; speedup 1.0000x reference)
//
#include <hip/hip_runtime.h>
#include <hip/hip_bf16.h>

// GCN: h1 = relu(norm_agg(x@W1) + b1); h2 = relu(norm_agg(h1@W2) + b2);
// g = mean_pool(h2, batch); out = sigmoid(g@Wfc + bfc)

#define N_NODES 131072
#define N_EDGES 2097152
#define N_GRAPHS 2048
#define IN_CH 12
#define HID 64
#define OUT_CH 4

// ---- degree ----
__global__ void deg_kernel(const int* __restrict__ dst, float* __restrict__ deg) {
    int e = blockIdx.x * 256 + threadIdx.x;
    atomicAdd(&deg[dst[e]], 1.0f);
}

__global__ void dinv_kernel(float* __restrict__ deg) {
    int i = blockIdx.x * 256 + threadIdx.x;
    deg[i] = rsqrtf(deg[i] + 1.0f);  // +1 for self loop
}

// ---- x @ W1 : [N,12] @ [12,64] ----
__global__ void xw1_kernel(const float* __restrict__ x, const float* __restrict__ W1,
                           float* __restrict__ h) {
    __shared__ float sW[IN_CH * HID];   // 768 floats
    __shared__ float sx[4][IN_CH];      // 4 nodes per block
    int tid = threadIdx.x;
    for (int i = tid; i < IN_CH * HID; i += 256) sW[i] = W1[i];
    int node0 = blockIdx.x * 4;
    if (tid < 4 * IN_CH) {
        int nl = tid / IN_CH, k = tid % IN_CH;
        sx[nl][k] = x[(node0 + nl) * IN_CH + k];
    }
    __syncthreads();
    int nl = tid >> 6, c = tid & 63;
    float acc = 0.0f;
#pragma unroll
    for (int k = 0; k < IN_CH; k++) acc += sx[nl][k] * sW[k * HID + c];
    h[(node0 + nl) * HID + c] = acc;
}

// ---- edge scatter: agg[dst] += h[src] * dinv[src]*dinv[dst] ----
__global__ void scatter_kernel(const int* __restrict__ src, const int* __restrict__ dst,
                               const float* __restrict__ dinv,
                               const float* __restrict__ h, float* __restrict__ agg) {
    int e = blockIdx.x * 4 + (threadIdx.x >> 6);
    int c = threadIdx.x & 63;
    int s = src[e], d = dst[e];
    float norm = dinv[s] * dinv[d];
    atomicAdd(&agg[d * HID + c], h[s * HID + c] * norm);
}

// ---- epilogue: agg = relu(agg + h*dinv^2 + b) (in place on agg) ----
__global__ void epi_kernel(const float* __restrict__ h, const float* __restrict__ dinv,
                           const float* __restrict__ b, float* __restrict__ agg) {
    int idx = blockIdx.x * 256 + threadIdx.x;  // over N*64
    int node = idx >> 6, c = idx & 63;
    float di = dinv[node];
    float v = agg[idx] + h[idx] * di * di + b[c];
    agg[idx] = fmaxf(v, 0.0f);
}

// ---- h @ W2 : [N,64] @ [64,64] ----
__global__ void hw2_kernel(const float* __restrict__ hin, const float* __restrict__ W2,
                           float* __restrict__ hout) {
    __shared__ float sW[HID * HID];  // 16 KB
    __shared__ float sh[4][HID];
    int tid = threadIdx.x;
    for (int i = tid; i < HID * HID; i += 256) sW[i] = W2[i];
    int node0 = blockIdx.x * 4;
    sh[tid >> 6][tid & 63] = hin[node0 * HID + tid];
    __syncthreads();
    int nl = tid >> 6, c = tid & 63;
    float acc = 0.0f;
#pragma unroll
    for (int k = 0; k < HID; k++) acc += sh[nl][k] * sW[k * HID + c];
    hout[(node0 + nl) * HID + c] = acc;
}

// ---- pool: pool[batch[n]] += h[n]; cnt[batch[n]] += 1 ----
__global__ void pool_kernel(const float* __restrict__ h, const int* __restrict__ batch,
                            float* __restrict__ pool, float* __restrict__ cnt) {
    int idx = blockIdx.x * 256 + threadIdx.x;  // over N*64
    int node = idx >> 6, c = idx & 63;
    int g = batch[node];
    atomicAdd(&pool[g * HID + c], h[idx]);
    if (c == 0) atomicAdd(&cnt[g], 1.0f);
}

// ---- final: out = sigmoid((pool/cnt) @ Wfc + bfc) ----
__global__ void final_kernel(const float* __restrict__ pool, const float* __restrict__ cnt,
                             const float* __restrict__ Wfc, const float* __restrict__ bfc,
                             float* __restrict__ out) {
    int idx = blockIdx.x * 256 + threadIdx.x;
    if (idx >= N_GRAPHS * OUT_CH) return;
    int g = idx >> 2, o = idx & 3;
    float inv = 1.0f / fmaxf(cnt[g], 1.0f);
    float acc = bfc[o];
#pragma unroll
    for (int k = 0; k < HID; k++) acc += pool[g * HID + k] * inv * Wfc[k * OUT_CH + o];
    out[idx] = 1.0f / (1.0f + expf(-acc));
}

extern "C" void kernel_launch(void* const* d_in, const int* in_sizes, int n_in,
                              void* d_out, int out_size, void* d_ws, size_t ws_size,
                              hipStream_t stream) {
    const float* x   = (const float*)d_in[0];
    const int* eidx  = (const int*)d_in[1];
    const int* batch = (const int*)d_in[2];
    const float* W1  = (const float*)d_in[3];
    const float* b1  = (const float*)d_in[4];
    const float* W2  = (const float*)d_in[5];
    const float* b2  = (const float*)d_in[6];
    const float* Wfc = (const float*)d_in[7];
    const float* bfc = (const float*)d_in[8];
    float* out = (float*)d_out;

    const int* src = eidx;
    const int* dst = eidx + N_EDGES;

    float* hA   = (float*)d_ws;                 // 32 MB
    float* hB   = hA + (size_t)N_NODES * HID;   // 32 MB
    float* dinv = hB + (size_t)N_NODES * HID;   // 512 KB (deg -> dinv in place)
    float* pool = dinv + N_NODES;               // 512 KB
    float* cnt  = pool + N_GRAPHS * HID;        // 8 KB

    // zero what accumulates
    hipMemsetAsync(dinv, 0, (size_t)N_NODES * 4, stream);
    hipMemsetAsync(pool, 0, (size_t)(N_GRAPHS * HID + N_GRAPHS) * 4, stream);
    hipMemsetAsync(hB, 0, (size_t)N_NODES * HID * 4, stream);

    deg_kernel<<<N_EDGES / 256, 256, 0, stream>>>(dst, dinv);
    dinv_kernel<<<N_NODES / 256, 256, 0, stream>>>(dinv);

    // layer 1
    xw1_kernel<<<N_NODES / 4, 256, 0, stream>>>(x, W1, hA);
    scatter_kernel<<<N_EDGES / 4, 256, 0, stream>>>(src, dst, dinv, hA, hB);
    epi_kernel<<<N_NODES * HID / 256, 256, 0, stream>>>(hA, dinv, b1, hB);
    // hB now holds h1 (relu'd)

    // layer 2
    hw2_kernel<<<N_NODES / 4, 256, 0, stream>>>(hB, W2, hA);  // hA = h1@W2
    hipMemsetAsync(hB, 0, (size_t)N_NODES * HID * 4, stream);
    scatter_kernel<<<N_EDGES / 4, 256, 0, stream>>>(src, dst, dinv, hA, hB);
    epi_kernel<<<N_NODES * HID / 256, 256, 0, stream>>>(hA, dinv, b2, hB);
    // hB now holds h2

    // pool + head
    pool_kernel<<<N_NODES * HID / 256, 256, 0, stream>>>(hB, batch, pool, cnt);
    final_kernel<<<(N_GRAPHS * OUT_CH + 255) / 256, 256, 0, stream>>>(pool, cnt, Wfc, bfc, out);
}

// Round 2
// 709.356 us; speedup vs baseline: 1.8874x; 1.8874x over previous
//
#include <hip/hip_runtime.h>
#include <hip/hip_bf16.h>

// GCN via device-built CSR (by dst) + gather aggregation (no scatter atomics).
// h1 = relu(agg(x@W1)+b1); h2 = relu(agg(h1@W2)+b2); out = sigmoid(meanpool(h2)@Wfc+bfc)

#define N_NODES 131072
#define N_EDGES 2097152
#define N_GRAPHS 2048
#define IN_CH 12
#define HID 64
#define OUT_CH 4

// ---- in-degree histogram (also CSR row counts) ----
__global__ void hist_kernel(const int* __restrict__ dst, int* __restrict__ cnt) {
    int e = blockIdx.x * 256 + threadIdx.x;
    atomicAdd(&cnt[dst[e]], 1);
}

// ---- scan phase 1: per-block exclusive scan + block sums; also dinv ----
__global__ void scan1_kernel(const int* __restrict__ cnt, int* __restrict__ rowptr,
                             int* __restrict__ bsum, float* __restrict__ dinv) {
    __shared__ int tmp[256];
    int i = blockIdx.x * 256 + threadIdx.x;
    int v = cnt[i];
    dinv[i] = rsqrtf((float)v + 1.0f);  // +1 self loop
    tmp[threadIdx.x] = v;
    __syncthreads();
    for (int off = 1; off < 256; off <<= 1) {
        int t = (threadIdx.x >= off) ? tmp[threadIdx.x - off] : 0;
        __syncthreads();
        tmp[threadIdx.x] += t;
        __syncthreads();
    }
    rowptr[i] = tmp[threadIdx.x] - v;  // exclusive
    if (threadIdx.x == 255) bsum[blockIdx.x] = tmp[255];
}

// ---- scan phase 2: exclusive scan of 512 block sums (single block) ----
__global__ void scan2_kernel(int* __restrict__ bsum) {
    __shared__ int tmp[512];
    int t = threadIdx.x;
    int v = bsum[t];
    tmp[t] = v;
    __syncthreads();
    for (int off = 1; off < 512; off <<= 1) {
        int u = (t >= off) ? tmp[t - off] : 0;
        __syncthreads();
        tmp[t] += u;
        __syncthreads();
    }
    bsum[t] = tmp[t] - v;  // exclusive
}

// ---- scan phase 3: add block offsets ----
__global__ void scan3_kernel(int* __restrict__ rowptr, const int* __restrict__ bsum) {
    int i = blockIdx.x * 256 + threadIdx.x;
    rowptr[i] += bsum[blockIdx.x];
}

// ---- CSR fill: csr_src[rowptr[d] + slot] = src ----
__global__ void fill_kernel(const int* __restrict__ src, const int* __restrict__ dst,
                            const int* __restrict__ rowptr, int* __restrict__ next,
                            int* __restrict__ csr_src) {
    int e = blockIdx.x * 256 + threadIdx.x;
    int d = dst[e];
    int pos = rowptr[d] + atomicAdd(&next[d], 1);
    csr_src[pos] = src[e];
}

// ---- x @ W1 : [N,12] @ [12,64], 16 nodes/block ----
__global__ void xw1_kernel(const float* __restrict__ x, const float* __restrict__ W1,
                           float* __restrict__ h) {
    __shared__ float sW[IN_CH * HID];  // 768 floats
    __shared__ float sx[16 * IN_CH];   // 192 floats
    int tid = threadIdx.x;
    for (int i = tid; i < IN_CH * HID; i += 256) sW[i] = W1[i];
    int node0 = blockIdx.x * 16;
    if (tid < 16 * IN_CH) sx[tid] = x[node0 * IN_CH + tid];
    __syncthreads();
    int c = tid & 63, nb = (tid >> 6) * 4;
    float a0 = 0, a1 = 0, a2 = 0, a3 = 0;
#pragma unroll
    for (int k = 0; k < IN_CH; k++) {
        float w = sW[k * HID + c];
        a0 += sx[(nb + 0) * IN_CH + k] * w;
        a1 += sx[(nb + 1) * IN_CH + k] * w;
        a2 += sx[(nb + 2) * IN_CH + k] * w;
        a3 += sx[(nb + 3) * IN_CH + k] * w;
    }
    h[(node0 + nb + 0) * HID + c] = a0;
    h[(node0 + nb + 1) * HID + c] = a1;
    h[(node0 + nb + 2) * HID + c] = a2;
    h[(node0 + nb + 3) * HID + c] = a3;
}

// ---- h @ W2 : [N,64] @ [64,64], 16 nodes/block, float4 LDS reads ----
__global__ void hw2_kernel(const float* __restrict__ hin, const float* __restrict__ W2,
                           float* __restrict__ hout) {
    __shared__ float sW[HID * HID];                 // 16 KB
    __shared__ __align__(16) float sh[16 * HID];    // 4 KB
    int tid = threadIdx.x;
    for (int i = tid; i < HID * HID; i += 256) sW[i] = W2[i];
    int node0 = blockIdx.x * 16;
    for (int i = tid; i < 16 * HID; i += 256) sh[i] = hin[node0 * HID + i];
    __syncthreads();
    int c = tid & 63, nb = (tid >> 6) * 4;
    float a0 = 0, a1 = 0, a2 = 0, a3 = 0;
#pragma unroll 4
    for (int k4 = 0; k4 < HID; k4 += 4) {
        float w0 = sW[(k4 + 0) * HID + c];
        float w1 = sW[(k4 + 1) * HID + c];
        float w2v = sW[(k4 + 2) * HID + c];
        float w3 = sW[(k4 + 3) * HID + c];
        float4 s0 = *(const float4*)&sh[(nb + 0) * HID + k4];
        float4 s1 = *(const float4*)&sh[(nb + 1) * HID + k4];
        float4 s2 = *(const float4*)&sh[(nb + 2) * HID + k4];
        float4 s3 = *(const float4*)&sh[(nb + 3) * HID + k4];
        a0 += s0.x * w0 + s0.y * w1 + s0.z * w2v + s0.w * w3;
        a1 += s1.x * w0 + s1.y * w1 + s1.z * w2v + s1.w * w3;
        a2 += s2.x * w0 + s2.y * w1 + s2.z * w2v + s2.w * w3;
        a3 += s3.x * w0 + s3.y * w1 + s3.z * w2v + s3.w * w3;
    }
    hout[(node0 + nb + 0) * HID + c] = a0;
    hout[(node0 + nb + 1) * HID + c] = a1;
    hout[(node0 + nb + 2) * HID + c] = a2;
    hout[(node0 + nb + 3) * HID + c] = a3;
}

// ---- gather-aggregate + self loop + bias + relu -> out ----
__global__ void agg_relu_kernel(const int* __restrict__ rowptr, const int* __restrict__ csr_src,
                                const float* __restrict__ dinv, const float* __restrict__ h,
                                const float* __restrict__ b, float* __restrict__ out) {
    int w = threadIdx.x >> 6, lane = threadIdx.x & 63;
    int node = blockIdx.x * 4 + w;
    int beg = rowptr[node];
    int end = (node == N_NODES - 1) ? N_EDGES : rowptr[node + 1];
    float dn = dinv[node];
    float acc = 0.0f;
    int j = beg;
    for (; j + 1 < end; j += 2) {
        int s0 = csr_src[j], s1 = csr_src[j + 1];
        float n0 = dinv[s0] * dn, n1 = dinv[s1] * dn;
        acc += h[s0 * HID + lane] * n0 + h[s1 * HID + lane] * n1;
    }
    if (j < end) {
        int s = csr_src[j];
        acc += h[s * HID + lane] * dinv[s] * dn;
    }
    float v = acc + h[node * HID + lane] * dn * dn + b[lane];
    out[node * HID + lane] = fmaxf(v, 0.0f);
}

// ---- gather-aggregate + relu + fused mean-pool accumulation ----
__global__ void agg_pool_kernel(const int* __restrict__ rowptr, const int* __restrict__ csr_src,
                                const float* __restrict__ dinv, const float* __restrict__ h,
                                const float* __restrict__ b, const int* __restrict__ batch,
                                float* __restrict__ pool, float* __restrict__ gcnt) {
    __shared__ float red[4][HID];
    __shared__ int gid[4];
    int w = threadIdx.x >> 6, lane = threadIdx.x & 63;
    int node = blockIdx.x * 4 + w;
    int beg = rowptr[node];
    int end = (node == N_NODES - 1) ? N_EDGES : rowptr[node + 1];
    float dn = dinv[node];
    float acc = 0.0f;
    int j = beg;
    for (; j + 1 < end; j += 2) {
        int s0 = csr_src[j], s1 = csr_src[j + 1];
        float n0 = dinv[s0] * dn, n1 = dinv[s1] * dn;
        acc += h[s0 * HID + lane] * n0 + h[s1 * HID + lane] * n1;
    }
    if (j < end) {
        int s = csr_src[j];
        acc += h[s * HID + lane] * dinv[s] * dn;
    }
    float v = fmaxf(acc + h[node * HID + lane] * dn * dn + b[lane], 0.0f);
    red[w][lane] = v;
    if (lane == 0) gid[w] = batch[node];
    __syncthreads();
    if (w == 0) {
        int g0 = gid[0], g1 = gid[1], g2 = gid[2], g3 = gid[3];
        if (g0 == g3) {  // batch sorted -> all equal
            atomicAdd(&pool[g0 * HID + lane],
                      red[0][lane] + red[1][lane] + red[2][lane] + red[3][lane]);
            if (lane == 0) atomicAdd(&gcnt[g0], 4.0f);
        } else {
            atomicAdd(&pool[g0 * HID + lane], red[0][lane]);
            atomicAdd(&pool[g1 * HID + lane], red[1][lane]);
            atomicAdd(&pool[g2 * HID + lane], red[2][lane]);
            atomicAdd(&pool[g3 * HID + lane], red[3][lane]);
            if (lane == 0) {
                atomicAdd(&gcnt[g0], 1.0f);
                atomicAdd(&gcnt[g1], 1.0f);
                atomicAdd(&gcnt[g2], 1.0f);
                atomicAdd(&gcnt[g3], 1.0f);
            }
        }
    }
}

// ---- final: out = sigmoid((pool/cnt) @ Wfc + bfc) ----
__global__ void final_kernel(const float* __restrict__ pool, const float* __restrict__ gcnt,
                             const float* __restrict__ Wfc, const float* __restrict__ bfc,
                             float* __restrict__ out) {
    int idx = blockIdx.x * 256 + threadIdx.x;
    if (idx >= N_GRAPHS * OUT_CH) return;
    int g = idx >> 2, o = idx & 3;
    float inv = 1.0f / fmaxf(gcnt[g], 1.0f);
    float acc = bfc[o];
#pragma unroll
    for (int k = 0; k < HID; k++) acc += pool[g * HID + k] * inv * Wfc[k * OUT_CH + o];
    out[idx] = 1.0f / (1.0f + expf(-acc));
}

extern "C" void kernel_launch(void* const* d_in, const int* in_sizes, int n_in,
                              void* d_out, int out_size, void* d_ws, size_t ws_size,
                              hipStream_t stream) {
    const float* x   = (const float*)d_in[0];
    const int* eidx  = (const int*)d_in[1];
    const int* batch = (const int*)d_in[2];
    const float* W1  = (const float*)d_in[3];
    const float* b1  = (const float*)d_in[4];
    const float* W2  = (const float*)d_in[5];
    const float* b2  = (const float*)d_in[6];
    const float* Wfc = (const float*)d_in[7];
    const float* bfc = (const float*)d_in[8];
    float* out = (float*)d_out;

    const int* src = eidx;
    const int* dst = eidx + N_EDGES;

    // workspace layout
    float* hA     = (float*)d_ws;                       // 8M floats (32 MB)
    float* hB     = hA + (size_t)N_NODES * HID;         // 8M floats (32 MB)
    float* dinv   = hB + (size_t)N_NODES * HID;         // 131072
    int*   cnt    = (int*)(dinv + N_NODES);             // 131072
    int*   next   = cnt + N_NODES;                      // 131072
    int*   rowptr = next + N_NODES;                     // 131072
    int*   bsum   = rowptr + N_NODES;                   // 512
    float* pool   = (float*)(bsum + 512);               // 2048*64
    float* gcnt   = pool + N_GRAPHS * HID;              // 2048
    int*   csr_src = (int*)(gcnt + N_GRAPHS);           // 2M ints (8 MB)

    // zero accumulators (cnt & next adjacent; pool & gcnt adjacent)
    hipMemsetAsync(cnt, 0, (size_t)2 * N_NODES * 4, stream);
    hipMemsetAsync(pool, 0, (size_t)(N_GRAPHS * HID + N_GRAPHS) * 4, stream);

    // build CSR by dst + dinv
    hist_kernel<<<N_EDGES / 256, 256, 0, stream>>>(dst, cnt);
    scan1_kernel<<<N_NODES / 256, 256, 0, stream>>>(cnt, rowptr, bsum, dinv);
    scan2_kernel<<<1, 512, 0, stream>>>(bsum);
    scan3_kernel<<<N_NODES / 256, 256, 0, stream>>>(rowptr, bsum);
    fill_kernel<<<N_EDGES / 256, 256, 0, stream>>>(src, dst, rowptr, next, csr_src);

    // layer 1
    xw1_kernel<<<N_NODES / 16, 256, 0, stream>>>(x, W1, hA);
    agg_relu_kernel<<<N_NODES / 4, 256, 0, stream>>>(rowptr, csr_src, dinv, hA, b1, hB);

    // layer 2 (pool fused into aggregation; h2 never materialized)
    hw2_kernel<<<N_NODES / 16, 256, 0, stream>>>(hB, W2, hA);
    agg_pool_kernel<<<N_NODES / 4, 256, 0, stream>>>(rowptr, csr_src, dinv, hA, b2, batch,
                                                     pool, gcnt);

    // head
    final_kernel<<<(N_GRAPHS * OUT_CH + 255) / 256, 256, 0, stream>>>(pool, gcnt, Wfc, bfc, out);
}

// Round 3
// 510.890 us; speedup vs baseline: 2.6206x; 1.3885x over previous
//
#include <hip/hip_runtime.h>
#include <hip/hip_bf16.h>

// GCN via device-built CSR (by dst, with precomputed edge norms) + MLP-optimized
// gather aggregation: wave = node, 4 subgroups x 16 lanes, float4 per lane,
// 8 edges in flight. No scatter atomics on features.

#define N_NODES 131072
#define N_EDGES 2097152
#define N_GRAPHS 2048
#define IN_CH 12
#define HID 64
#define OUT_CH 4

// ---- in-degree histogram ----
__global__ void hist_kernel(const int* __restrict__ dst, int* __restrict__ cnt) {
    int e = blockIdx.x * 256 + threadIdx.x;
    atomicAdd(&cnt[dst[e]], 1);
}

// ---- scan phase 1: per-block exclusive scan + block sums; also dinv ----
__global__ void scan1_kernel(const int* __restrict__ cnt, int* __restrict__ rowptr,
                             int* __restrict__ bsum, float* __restrict__ dinv) {
    __shared__ int tmp[256];
    int i = blockIdx.x * 256 + threadIdx.x;
    int v = cnt[i];
    dinv[i] = rsqrtf((float)v + 1.0f);  // +1 self loop
    tmp[threadIdx.x] = v;
    __syncthreads();
    for (int off = 1; off < 256; off <<= 1) {
        int t = (threadIdx.x >= off) ? tmp[threadIdx.x - off] : 0;
        __syncthreads();
        tmp[threadIdx.x] += t;
        __syncthreads();
    }
    rowptr[i] = tmp[threadIdx.x] - v;  // exclusive
    if (threadIdx.x == 255) bsum[blockIdx.x] = tmp[255];
}

// ---- scan phase 2: exclusive scan of 512 block sums ----
__global__ void scan2_kernel(int* __restrict__ bsum) {
    __shared__ int tmp[512];
    int t = threadIdx.x;
    int v = bsum[t];
    tmp[t] = v;
    __syncthreads();
    for (int off = 1; off < 512; off <<= 1) {
        int u = (t >= off) ? tmp[t - off] : 0;
        __syncthreads();
        tmp[t] += u;
        __syncthreads();
    }
    bsum[t] = tmp[t] - v;  // exclusive
}

// ---- scan phase 3: add block offsets; emit rowptr + working copy ----
__global__ void scan3_kernel(int* __restrict__ rowptr, const int* __restrict__ bsum,
                             int* __restrict__ rowptr_work) {
    int i = blockIdx.x * 256 + threadIdx.x;
    int r = rowptr[i] + bsum[blockIdx.x];
    rowptr[i] = r;
    rowptr_work[i] = r;  // fill's cursor; after fill it equals row END pointer
}

// ---- CSR fill: csr[pos] = {src, norm} ----
__global__ void fill_kernel(const int* __restrict__ src, const int* __restrict__ dst,
                            const float* __restrict__ dinv, int* __restrict__ rowptr_work,
                            int2* __restrict__ csr) {
    int e = blockIdx.x * 256 + threadIdx.x;
    int s = src[e], d = dst[e];
    int pos = atomicAdd(&rowptr_work[d], 1);
    csr[pos] = make_int2(s, __float_as_int(dinv[s] * dinv[d]));
}

// ---- shared gather body: returns per-lane float4 partial (all lanes hold full sum) ----
__device__ __forceinline__ float4 agg_body(int node, const int* __restrict__ rowptr,
                                           const int* __restrict__ rowend,
                                           const int2* __restrict__ csr,
                                           const float* __restrict__ h,
                                           int sub, int q) {
    int beg = rowptr[node];
    int end = rowend[node];
    float4 a0 = {0, 0, 0, 0}, a1 = {0, 0, 0, 0};
    int j = beg;
    for (; j + 7 < end; j += 8) {
        int2 e0 = csr[j + sub];
        int2 e1 = csr[j + 4 + sub];
        float4 h0 = *(const float4*)&h[e0.x * HID + 4 * q];
        float4 h1 = *(const float4*)&h[e1.x * HID + 4 * q];
        float n0 = __int_as_float(e0.y), n1 = __int_as_float(e1.y);
        a0.x += n0 * h0.x; a0.y += n0 * h0.y; a0.z += n0 * h0.z; a0.w += n0 * h0.w;
        a1.x += n1 * h1.x; a1.y += n1 * h1.y; a1.z += n1 * h1.z; a1.w += n1 * h1.w;
    }
    for (; j + sub < end; j += 4) {
        int2 e0 = csr[j + sub];
        float4 h0 = *(const float4*)&h[e0.x * HID + 4 * q];
        float n0 = __int_as_float(e0.y);
        a0.x += n0 * h0.x; a0.y += n0 * h0.y; a0.z += n0 * h0.z; a0.w += n0 * h0.w;
    }
    float4 acc;
    acc.x = a0.x + a1.x; acc.y = a0.y + a1.y; acc.z = a0.z + a1.z; acc.w = a0.w + a1.w;
    // reduce across the 4 subgroups (lanes ^16, ^32)
    acc.x += __shfl_xor(acc.x, 16, 64); acc.y += __shfl_xor(acc.y, 16, 64);
    acc.z += __shfl_xor(acc.z, 16, 64); acc.w += __shfl_xor(acc.w, 16, 64);
    acc.x += __shfl_xor(acc.x, 32, 64); acc.y += __shfl_xor(acc.y, 32, 64);
    acc.z += __shfl_xor(acc.z, 32, 64); acc.w += __shfl_xor(acc.w, 32, 64);
    return acc;
}

// ---- gather-aggregate + self loop + bias + relu -> out ----
__global__ void agg_relu_kernel(const int* __restrict__ rowptr, const int* __restrict__ rowend,
                                const int2* __restrict__ csr, const float* __restrict__ dinv,
                                const float* __restrict__ h, const float* __restrict__ b,
                                float* __restrict__ out) {
    int tid = threadIdx.x;
    int wid = tid >> 6, lane = tid & 63;
    int sub = lane >> 4, q = lane & 15;
    int node = blockIdx.x * 4 + wid;
    float dn = dinv[node];
    float4 acc = agg_body(node, rowptr, rowend, csr, h, sub, q);
    float4 self = *(const float4*)&h[node * HID + 4 * q];
    float4 bb = *(const float4*)&b[4 * q];
    float dn2 = dn * dn;
    float4 v;
    v.x = fmaxf(acc.x + dn2 * self.x + bb.x, 0.0f);
    v.y = fmaxf(acc.y + dn2 * self.y + bb.y, 0.0f);
    v.z = fmaxf(acc.z + dn2 * self.z + bb.z, 0.0f);
    v.w = fmaxf(acc.w + dn2 * self.w + bb.w, 0.0f);
    if (sub == 0) *(float4*)&out[node * HID + 4 * q] = v;
}

// ---- gather-aggregate + relu + fused mean-pool ----
__global__ void agg_pool_kernel(const int* __restrict__ rowptr, const int* __restrict__ rowend,
                                const int2* __restrict__ csr, const float* __restrict__ dinv,
                                const float* __restrict__ h, const float* __restrict__ b,
                                const int* __restrict__ batch, float* __restrict__ pool,
                                float* __restrict__ gcnt) {
    __shared__ float red[4][HID];
    __shared__ int gid[4];
    int tid = threadIdx.x;
    int wid = tid >> 6, lane = tid & 63;
    int sub = lane >> 4, q = lane & 15;
    int node = blockIdx.x * 4 + wid;
    float dn = dinv[node];
    float4 acc = agg_body(node, rowptr, rowend, csr, h, sub, q);
    float4 self = *(const float4*)&h[node * HID + 4 * q];
    float4 bb = *(const float4*)&b[4 * q];
    float dn2 = dn * dn;
    float4 v;
    v.x = fmaxf(acc.x + dn2 * self.x + bb.x, 0.0f);
    v.y = fmaxf(acc.y + dn2 * self.y + bb.y, 0.0f);
    v.z = fmaxf(acc.z + dn2 * self.z + bb.z, 0.0f);
    v.w = fmaxf(acc.w + dn2 * self.w + bb.w, 0.0f);
    if (sub == 0) *(float4*)&red[wid][4 * q] = v;
    if (lane == 0) gid[wid] = batch[node];
    __syncthreads();
    if (wid == 0) {
        int c = lane;
        float r0 = red[0][c], r1 = red[1][c], r2 = red[2][c], r3 = red[3][c];
        int g0 = gid[0], g1 = gid[1], g2 = gid[2], g3 = gid[3];
        if (g0 == g3) {  // batch sorted -> usually all equal
            atomicAdd(&pool[g0 * HID + c], r0 + r1 + r2 + r3);
            if (c == 0) atomicAdd(&gcnt[g0], 4.0f);
        } else {
            atomicAdd(&pool[g0 * HID + c], r0);
            atomicAdd(&pool[g1 * HID + c], r1);
            atomicAdd(&pool[g2 * HID + c], r2);
            atomicAdd(&pool[g3 * HID + c], r3);
            if (c == 0) {
                atomicAdd(&gcnt[g0], 1.0f);
                atomicAdd(&gcnt[g1], 1.0f);
                atomicAdd(&gcnt[g2], 1.0f);
                atomicAdd(&gcnt[g3], 1.0f);
            }
        }
    }
}

// ---- x @ W1 : [N,12] @ [12,64], 16 nodes/block ----
__global__ void xw1_kernel(const float* __restrict__ x, const float* __restrict__ W1,
                           float* __restrict__ h) {
    __shared__ float sW[IN_CH * HID];
    __shared__ float sx[16 * IN_CH];
    int tid = threadIdx.x;
    for (int i = tid; i < IN_CH * HID; i += 256) sW[i] = W1[i];
    int node0 = blockIdx.x * 16;
    if (tid < 16 * IN_CH) sx[tid] = x[node0 * IN_CH + tid];
    __syncthreads();
    int c = tid & 63, nb = (tid >> 6) * 4;
    float a0 = 0, a1 = 0, a2 = 0, a3 = 0;
#pragma unroll
    for (int k = 0; k < IN_CH; k++) {
        float w = sW[k * HID + c];
        a0 += sx[(nb + 0) * IN_CH + k] * w;
        a1 += sx[(nb + 1) * IN_CH + k] * w;
        a2 += sx[(nb + 2) * IN_CH + k] * w;
        a3 += sx[(nb + 3) * IN_CH + k] * w;
    }
    h[(node0 + nb + 0) * HID + c] = a0;
    h[(node0 + nb + 1) * HID + c] = a1;
    h[(node0 + nb + 2) * HID + c] = a2;
    h[(node0 + nb + 3) * HID + c] = a3;
}

// ---- h @ W2 : [N,64] @ [64,64], 16 nodes/block ----
__global__ void hw2_kernel(const float* __restrict__ hin, const float* __restrict__ W2,
                           float* __restrict__ hout) {
    __shared__ float sW[HID * HID];
    __shared__ __align__(16) float sh[16 * HID];
    int tid = threadIdx.x;
    for (int i = tid; i < HID * HID; i += 256) sW[i] = W2[i];
    int node0 = blockIdx.x * 16;
    for (int i = tid; i < 16 * HID; i += 256) sh[i] = hin[node0 * HID + i];
    __syncthreads();
    int c = tid & 63, nb = (tid >> 6) * 4;
    float a0 = 0, a1 = 0, a2 = 0, a3 = 0;
#pragma unroll 4
    for (int k4 = 0; k4 < HID; k4 += 4) {
        float w0 = sW[(k4 + 0) * HID + c];
        float w1 = sW[(k4 + 1) * HID + c];
        float w2v = sW[(k4 + 2) * HID + c];
        float w3 = sW[(k4 + 3) * HID + c];
        float4 s0 = *(const float4*)&sh[(nb + 0) * HID + k4];
        float4 s1 = *(const float4*)&sh[(nb + 1) * HID + k4];
        float4 s2 = *(const float4*)&sh[(nb + 2) * HID + k4];
        float4 s3 = *(const float4*)&sh[(nb + 3) * HID + k4];
        a0 += s0.x * w0 + s0.y * w1 + s0.z * w2v + s0.w * w3;
        a1 += s1.x * w0 + s1.y * w1 + s1.z * w2v + s1.w * w3;
        a2 += s2.x * w0 + s2.y * w1 + s2.z * w2v + s2.w * w3;
        a3 += s3.x * w0 + s3.y * w1 + s3.z * w2v + s3.w * w3;
    }
    hout[(node0 + nb + 0) * HID + c] = a0;
    hout[(node0 + nb + 1) * HID + c] = a1;
    hout[(node0 + nb + 2) * HID + c] = a2;
    hout[(node0 + nb + 3) * HID + c] = a3;
}

// ---- final: out = sigmoid((pool/cnt) @ Wfc + bfc) ----
__global__ void final_kernel(const float* __restrict__ pool, const float* __restrict__ gcnt,
                             const float* __restrict__ Wfc, const float* __restrict__ bfc,
                             float* __restrict__ out) {
    int idx = blockIdx.x * 256 + threadIdx.x;
    if (idx >= N_GRAPHS * OUT_CH) return;
    int g = idx >> 2, o = idx & 3;
    float inv = 1.0f / fmaxf(gcnt[g], 1.0f);
    float acc = bfc[o];
#pragma unroll
    for (int k = 0; k < HID; k++) acc += pool[g * HID + k] * inv * Wfc[k * OUT_CH + o];
    out[idx] = 1.0f / (1.0f + expf(-acc));
}

extern "C" void kernel_launch(void* const* d_in, const int* in_sizes, int n_in,
                              void* d_out, int out_size, void* d_ws, size_t ws_size,
                              hipStream_t stream) {
    const float* x   = (const float*)d_in[0];
    const int* eidx  = (const int*)d_in[1];
    const int* batch = (const int*)d_in[2];
    const float* W1  = (const float*)d_in[3];
    const float* b1  = (const float*)d_in[4];
    const float* W2  = (const float*)d_in[5];
    const float* b2  = (const float*)d_in[6];
    const float* Wfc = (const float*)d_in[7];
    const float* bfc = (const float*)d_in[8];
    float* out = (float*)d_out;

    const int* src = eidx;
    const int* dst = eidx + N_EDGES;

    // workspace layout (~82 MB)
    float* hA   = (float*)d_ws;                        // 32 MB
    float* hB   = hA + (size_t)N_NODES * HID;          // 32 MB
    int2*  csr  = (int2*)(hB + (size_t)N_NODES * HID); // 16 MB {src, norm}
    float* dinv = (float*)(csr + N_EDGES);             // 512 KB
    int*   cnt  = (int*)(dinv + N_NODES);              // 512 KB (reused as rowptr_work)
    int*   rowptr = cnt + N_NODES;                     // 512 KB
    int*   bsum = rowptr + N_NODES;                    // 2 KB
    float* pool = (float*)(bsum + 512);                // 512 KB
    float* gcnt = pool + N_GRAPHS * HID;               // 8 KB
    int*   rowptr_work = cnt;                          // alias: cnt dead after scan1

    hipMemsetAsync(cnt, 0, (size_t)N_NODES * 4, stream);
    hipMemsetAsync(pool, 0, (size_t)(N_GRAPHS * HID + N_GRAPHS) * 4, stream);

    // build CSR (by dst) with per-edge norms
    hist_kernel<<<N_EDGES / 256, 256, 0, stream>>>(dst, cnt);
    scan1_kernel<<<N_NODES / 256, 256, 0, stream>>>(cnt, rowptr, bsum, dinv);
    scan2_kernel<<<1, 512, 0, stream>>>(bsum);
    scan3_kernel<<<N_NODES / 256, 256, 0, stream>>>(rowptr, bsum, rowptr_work);
    fill_kernel<<<N_EDGES / 256, 256, 0, stream>>>(src, dst, dinv, rowptr_work, csr);
    // rowptr_work[d] now equals row END pointer

    // layer 1
    xw1_kernel<<<N_NODES / 16, 256, 0, stream>>>(x, W1, hA);
    agg_relu_kernel<<<N_NODES / 4, 256, 0, stream>>>(rowptr, rowptr_work, csr, dinv, hA, b1, hB);

    // layer 2 (pool fused; h2 never materialized)
    hw2_kernel<<<N_NODES / 16, 256, 0, stream>>>(hB, W2, hA);
    agg_pool_kernel<<<N_NODES / 4, 256, 0, stream>>>(rowptr, rowptr_work, csr, dinv, hA, b2,
                                                     batch, pool, gcnt);

    // head
    final_kernel<<<(N_GRAPHS * OUT_CH + 255) / 256, 256, 0, stream>>>(pool, gcnt, Wfc, bfc, out);
}